// Round 14
// baseline (724.879 us; speedup 1.0000x reference)
//
#include <hip/hip_runtime.h>
#include <hip/hip_bf16.h>

typedef __attribute__((ext_vector_type(4)))  float  f32x4;
typedef __attribute__((ext_vector_type(16))) float  f32x16;
typedef __attribute__((ext_vector_type(8)))  __bf16 bf16x8;
typedef __attribute__((ext_vector_type(4)))  __bf16 bf16x4;
typedef __attribute__((ext_vector_type(4)))  unsigned int u32x4;

constexpr int S_LEN = 2048, DMODEL = 3584, NH = 28, NKV = 4, HD = 128, NREP = 7;
// 128^-0.5 * log2(e): softmax computed in base-2 (exp2f == bare v_exp_f32)
constexpr float SCALE_LOG2 = 0.1275174331f;

__device__ __forceinline__ unsigned int pack2(float a, float b) {
  unsigned short ua = __builtin_bit_cast(unsigned short, (__bf16)a);
  unsigned short ub = __builtin_bit_cast(unsigned short, (__bf16)b);
  return (unsigned int)ua | ((unsigned int)ub << 16);
}

// ---------------- fused f32 -> bf16 convert (5 tensors) + ctr zero ----------------
__global__ void cvt5_kernel(const float* __restrict__ s0, const float* __restrict__ s1,
                            const float* __restrict__ s2, const float* __restrict__ s3,
                            const float* __restrict__ s4,
                            __bf16* __restrict__ d0, __bf16* __restrict__ d1,
                            __bf16* __restrict__ d2, __bf16* __restrict__ d3,
                            __bf16* __restrict__ d4,
                            int n0, int n1, int n2, int n3, int* __restrict__ ctr, int total) {
  if (blockIdx.x == 0 && threadIdx.x == 0) *ctr = 0;
  for (int i = blockIdx.x * blockDim.x + threadIdx.x; i < total; i += gridDim.x * blockDim.x) {
    const float* s; __bf16* d; int j = i;
    if (j < n0) { s = s0; d = d0; }
    else { j -= n0;
      if (j < n1) { s = s1; d = d1; }
      else { j -= n1;
        if (j < n2) { s = s2; d = d2; }
        else { j -= n2;
          if (j < n3) { s = s3; d = d3; }
          else { j -= n3; s = s4; d = d4; }
        }
      }
    }
    float4 v = reinterpret_cast<const float4*>(s)[j];
    bf16x4 o;
    o[0] = (__bf16)v.x; o[1] = (__bf16)v.y; o[2] = (__bf16)v.z; o[3] = (__bf16)v.w;
    reinterpret_cast<bf16x4*>(d)[j] = o;
  }
}

#define GLDS16(gsrc, ldst)                                                              \
  __builtin_amdgcn_global_load_lds((const __attribute__((address_space(1))) void*)(gsrc),\
                                   (__attribute__((address_space(3))) void*)(ldst), 16, 0, 0)

// ============ 256x256 GEMM: R6 loop + B-fragment one-ahead prefetch ============
template <int MODE>
__global__ __launch_bounds__(512, 2) void gemm256(
    const __bf16* __restrict__ A, const __bf16* __restrict__ Bw,
    const float* __restrict__ bias, void* __restrict__ Cout,
    int M, int N, int K,
    const float* __restrict__ fcos, const float* __restrict__ fsin,
    const int* __restrict__ sp_ptr, float scale)
{
  extern __shared__ char smem[];  // [0,64K): A slots[4][16K]; [64K,128K): B slots[4][16K]
  const int tid = threadIdx.x;
  const int lane = tid & 63, wid = tid >> 6;
  const int wm = wid >> 2, wn = wid & 3;
  const int l15 = lane & 15, g = (lane >> 4) & 3;

  const int chunk = gridDim.x >> 3;
  const int wg = (blockIdx.x & 7) * chunk + (blockIdx.x >> 3);
  const int nbx = N >> 8;
  const int by = wg / nbx, bx = wg % nbx;
  const int row0 = by * 256, col0 = bx * 256;

  const int srL   = 16 * (tid >> 6) + ((tid >> 2) & 15);
  const int cperm = ((tid & 3) * 8) ^ (((tid >> 5) & 1) * 16);
  const __bf16* pA0 = A + (size_t)(row0 + srL) * K + cperm;
  const __bf16* pA1 = pA0 + (size_t)128 * K;
  const __bf16* pB0 = Bw + (size_t)(col0 + srL) * K + cperm;
  const __bf16* pB1 = pB0 + (size_t)128 * K;
  char* ldsA = smem + tid * 16;
  char* ldsB = smem + 65536 + tid * 16;

  const int sw = ((l15 >> 3) & 1) << 5;
  const int aoff = wm * 8192 + l15 * 64 + ((g * 16) ^ sw);
  const int boff = 65536 + wn * 4096 + l15 * 64 + ((g * 16) ^ sw);

  f32x4 acc[8][4] = {};
  const int nt = K >> 5;  // 112 (even)
  bf16x8 bE[4], bO[4];

#pragma unroll
  for (int pt = 0; pt < 3; pt++) {
    const size_t ko = (size_t)pt * 32;
    char* sA = ldsA + pt * 16384;
    char* sB = ldsB + pt * 16384;
    GLDS16(pA0 + ko, sA);
    GLDS16(pA1 + ko, sA + 8192);
    GLDS16(pB0 + ko, sB);
    GLDS16(pB1 + ko, sB + 8192);
  }
  asm volatile("s_waitcnt vmcnt(4)" ::: "memory");   // batches 0,1 resident
  __builtin_amdgcn_s_barrier();
  __builtin_amdgcn_sched_barrier(0);
  {
    const char* sb0 = smem + boff;  // slot 0
#pragma unroll
    for (int fn = 0; fn < 4; fn++)
      bE[fn] = *reinterpret_cast<const bf16x8*>(sb0 + fn * 1024);
  }

#define GTILE(T, BC, BN)                                                                \
  do {                                                                                  \
    const char* sa = smem + ((T) & 3) * 16384 + aoff;                                   \
    bf16x8 a0[4], a1[4];                                                                \
    _Pragma("unroll")                                                                   \
    for (int fm = 0; fm < 4; fm++)                                                      \
      a0[fm] = *reinterpret_cast<const bf16x8*>(sa + fm * 1024);                        \
    _Pragma("unroll")                                                                   \
    for (int fm = 0; fm < 4; fm++)                                                      \
      a1[fm] = *reinterpret_cast<const bf16x8*>(sa + (4 + fm) * 1024);                  \
    const bool hasnext = (T) + 1 < nt;                                                  \
    if (hasnext) {                                                                      \
      const char* sbn = smem + (((T) + 1) & 3) * 16384 + boff;                          \
      _Pragma("unroll")                                                                 \
      for (int fn = 0; fn < 4; fn++)                                                    \
        BN[fn] = *reinterpret_cast<const bf16x8*>(sbn + fn * 1024);                     \
    }                                                                                   \
    if ((T) + 3 < nt) {                                                                 \
      const size_t ko = (size_t)((T) + 3) * 32;                                         \
      char* sA = ldsA + (((T) + 3) & 3) * 16384;                                        \
      char* sB = ldsB + (((T) + 3) & 3) * 16384;                                        \
      GLDS16(pA0 + ko, sA);                                                             \
      GLDS16(pA1 + ko, sA + 8192);                                                      \
      GLDS16(pB0 + ko, sB);                                                             \
      GLDS16(pB1 + ko, sB + 8192);                                                      \
    }                                                                                   \
    asm volatile("s_waitcnt lgkmcnt(8)" ::: "memory");                                  \
    __builtin_amdgcn_sched_barrier(0);                                                  \
    __builtin_amdgcn_s_setprio(1);                                                      \
    _Pragma("unroll")                                                                   \
    for (int fn = 0; fn < 4; fn++)                                                      \
      _Pragma("unroll")                                                                 \
      for (int fm = 0; fm < 4; fm++)                                                    \
        acc[fm][fn] = __builtin_amdgcn_mfma_f32_16x16x32_bf16(a0[fm], BC[fn],           \
                                                              acc[fm][fn], 0, 0, 0);   \
    __builtin_amdgcn_s_setprio(0);                                                      \
    if (hasnext) asm volatile("s_waitcnt lgkmcnt(4)" ::: "memory");                     \
    else         asm volatile("s_waitcnt lgkmcnt(0)" ::: "memory");                     \
    __builtin_amdgcn_sched_barrier(0);                                                  \
    __builtin_amdgcn_s_setprio(1);                                                      \
    _Pragma("unroll")                                                                   \
    for (int fn = 0; fn < 4; fn++)                                                      \
      _Pragma("unroll")                                                                 \
      for (int fm = 0; fm < 4; fm++)                                                    \
        acc[4 + fm][fn] = __builtin_amdgcn_mfma_f32_16x16x32_bf16(a1[fm], BC[fn],       \
                                                                  acc[4 + fm][fn],     \
                                                                  0, 0, 0);            \
    __builtin_amdgcn_s_setprio(0);                                                      \
    if ((T) < nt - 3) asm volatile("s_waitcnt vmcnt(4)" ::: "memory");                  \
    else              asm volatile("s_waitcnt vmcnt(0)" ::: "memory");                  \
    __builtin_amdgcn_s_barrier();                                                       \
    __builtin_amdgcn_sched_barrier(0);                                                  \
  } while (0)

  for (int t = 0; t < nt; t += 2) {
    GTILE(t, bE, bO);
    GTILE(t + 1, bO, bE);
  }
#undef GTILE

  if constexpr (MODE == 0) {
    float* C = (float*)Cout;
#pragma unroll
    for (int fm = 0; fm < 8; fm++) {
      const int row = row0 + wm * 128 + fm * 16 + 4 * g;
#pragma unroll
      for (int fn = 0; fn < 4; fn++) {
        const int col = col0 + wn * 64 + fn * 16 + l15;
#pragma unroll
        for (int r = 0; r < 4; r++)
          C[(size_t)(row + r) * N + col] = acc[fm][fn][r];
      }
    }
  } else {
    __bf16* C = (__bf16*)Cout;
    const int sp = sp_ptr[0];
    float bval[4];
#pragma unroll
    for (int fn = 0; fn < 4; fn++) bval[fn] = bias[col0 + wn * 64 + fn * 16 + l15];
#pragma unroll
    for (int fm = 0; fm < 8; fm++) {
#pragma unroll
      for (int fn = 0; fn < 4; fn++) {
        const int col = col0 + wn * 64 + fn * 16 + l15;
        const int i = (col & (HD - 1)) >> 1;
#pragma unroll
        for (int r = 0; r < 4; r++) {
          const int row = row0 + wm * 128 + fm * 16 + 4 * g + r;
          float y = acc[fm][fn][r] + bval[fn];
          float p = __shfl_xor(y, 1);
          const int spos = sp + (row & (S_LEN - 1));
          const float c = fcos[spos * (HD / 2) + i];
          const float sn = fsin[spos * (HD / 2) + i];
          y = (col & 1) ? (p * sn + y * c) : (y * c - p * sn);
          C[(size_t)row * N + col] = (__bf16)(y * scale);
        }
      }
    }
  }
}

// ------- fused K+V projection GEMM; V written DIRECTLY transposed to Vt -------
__global__ __launch_bounds__(256) void gemm_kv(
    const __bf16* __restrict__ A,
    const __bf16* __restrict__ Wk, const float* __restrict__ bk, __bf16* __restrict__ Ko,
    const __bf16* __restrict__ Wv, const float* __restrict__ bv, __bf16* __restrict__ Vt,
    const float* __restrict__ fcos, const float* __restrict__ fsin,
    const int* __restrict__ sp_ptr)
{
  constexpr int N = 512, K = 3584;
  __shared__ __bf16 As[128 * 32];
  __shared__ __bf16 Bs[128 * 32];
  const int tid = threadIdx.x;
  const int lane = tid & 63, wid = tid >> 6;
  const int l15 = lane & 15, g = lane >> 4;
  const int wr = wid >> 1, wc = wid & 1;
  const bool isK = blockIdx.x < 4;
  const __bf16* Bw = isK ? Wk : Wv;
  const float* bias = isK ? bk : bv;
  const int row0 = blockIdx.y * 128;
  const int col0 = (blockIdx.x & 3) * 128;

  f32x4 acc[4][4] = {};

  const int srow = tid >> 2;
  const int scol = (tid & 3) * 8;
  const __bf16* Ag0 = A + (size_t)(row0 + srow) * K + scol;
  const __bf16* Ag1 = Ag0 + (size_t)64 * K;
  const __bf16* Bg0 = Bw + (size_t)(col0 + srow) * K + scol;
  const __bf16* Bg1 = Bg0 + (size_t)64 * K;
  __bf16* As0 = As + tid * 8;
  __bf16* As1 = As + 2048 + tid * 8;
  __bf16* Bs0 = Bs + tid * 8;
  __bf16* Bs1 = Bs + 2048 + tid * 8;

  for (int k0 = 0; k0 < K; k0 += 32) {
    GLDS16(Ag0 + k0, As0);
    GLDS16(Ag1 + k0, As1);
    GLDS16(Bg0 + k0, Bs0);
    GLDS16(Bg1 + k0, Bs1);
    __syncthreads();
    bf16x8 af[4], bfr[4];
#pragma unroll
    for (int m = 0; m < 4; m++)
      af[m] = *reinterpret_cast<const bf16x8*>(As + (wr * 64 + m * 16 + l15) * 32 + g * 8);
#pragma unroll
    for (int n = 0; n < 4; n++)
      bfr[n] = *reinterpret_cast<const bf16x8*>(Bs + (wc * 64 + n * 16 + l15) * 32 + g * 8);
#pragma unroll
    for (int m = 0; m < 4; m++)
#pragma unroll
      for (int n = 0; n < 4; n++)
        acc[m][n] = __builtin_amdgcn_mfma_f32_16x16x32_bf16(af[m], bfr[n], acc[m][n], 0, 0, 0);
    __syncthreads();
  }

  const int sp = sp_ptr[0];
  if (isK) {
#pragma unroll
    for (int m = 0; m < 4; m++) {
#pragma unroll
      for (int n = 0; n < 4; n++) {
        const int col = col0 + wc * 64 + n * 16 + l15;
        const float bval = bias[col];
        f32x4 v = acc[m][n];
#pragma unroll
        for (int r = 0; r < 4; r++) {
          const int row = row0 + wr * 64 + m * 16 + 4 * g + r;
          float y = v[r] + bval;
          float p = __shfl_xor(y, 1);
          const int i = (col & (HD - 1)) >> 1;
          const int spos = sp + (row & (S_LEN - 1));
          const float c = fcos[spos * (HD / 2) + i];
          const float sn = fsin[spos * (HD / 2) + i];
          y = (col & 1) ? (p * sn + y * c) : (y * c - p * sn);
          Ko[(size_t)row * N + col] = (__bf16)y;
        }
      }
    }
  } else {
    const int b4kv = ((row0 >> 11) * 4) + (blockIdx.x & 3);
    __bf16* vbase = Vt + ((size_t)b4kv << 18);  // 128*2048
#pragma unroll
    for (int m = 0; m < 4; m++) {
#pragma unroll
      for (int n = 0; n < 4; n++) {
        const int d = wc * 64 + n * 16 + l15;
        const float bval = bias[col0 + d];
        const int s0 = (row0 + wr * 64 + m * 16 + 4 * g) & (S_LEN - 1);
        f32x4 v = acc[m][n];
        bf16x4 o;
#pragma unroll
        for (int r = 0; r < 4; r++) o[r] = (__bf16)(v[r] + bval);
        *reinterpret_cast<bf16x4*>(vbase + (size_t)d * S_LEN + s0) = o;
      }
    }
  }
}

// -------- Flash attention: 8-wave blocks (512 thr), K/V tile shared by 256 q-rows,
// persistent blocks + LPT dynamic queue, double-buffered K/V --------
__global__ __launch_bounds__(512, 4) void attn_kernel(
    const __bf16* __restrict__ Qb, const __bf16* __restrict__ Kb,
    const __bf16* __restrict__ Vt, __bf16* __restrict__ Ob, int* __restrict__ ctr)
{
  __shared__ __align__(16) char asmem[65536];
  __shared__ int jsh;

  const int tid = threadIdx.x, lane = tid & 63, wid = tid >> 6;  // wid 0..7
  const int l31 = lane & 31, hh = lane >> 5;

  // staging maps (512 threads): K [64][128] in 2 passes of 32 rows;
  // V [128][64] in 2 passes of 64 rows. Pre-swizzled source, linear dest (rule 21).
  const int trow = tid >> 4;                                   // 0..31
  const int kcol = (((tid & 15) * 16) ^ ((trow & 7) << 4)) >> 1;
  const int vrow = tid >> 3;                                   // 0..63
  const int vcol = (((tid & 7) * 16) ^ ((vrow & 7) << 4)) >> 1;

  constexpr int NITEMS = 8 * NH * 2;  // 448 (8 q-blocks of 256 rows)

  while (true) {
    if (tid == 0) jsh = atomicAdd(ctr, 1);
    __syncthreads();  // broadcast jsh + fences prev epilogue LDS reads vs STAGE(0)
    const int j = jsh;
    if (j >= NITEMS) break;

    const int qi = 7 - (j / 56);         // q-block (256 rows), LPT descending
    const int r56 = j % 56;
    const int h = r56 >> 1, b = r56 & 1;
    const int kvh = h / NREP;
    const int qw = qi * 256 + wid * 32;  // wave's first q row
    const int qg = qw + l31;

    const __bf16* Kbase = Kb + ((size_t)b * S_LEN * NKV + kvh) * HD;
    const __bf16* Vbase = Vt + ((size_t)b * NKV + kvh) * (size_t)HD * S_LEN;

    bf16x8 qf[8];
    {
      const __bf16* qp = Qb + (((size_t)b * S_LEN + qg) * NH + h) * HD + hh * 8;
#pragma unroll
      for (int c = 0; c < 8; c++) qf[c] = *reinterpret_cast<const bf16x8*>(qp + c * 16);
    }

    f32x16 o[4] = {};
    float mrun = -3.0e38f, lsum = 0.0f;

    const int ntiles = 4 * qi + 4;  // even -> last tile reads slot 1

#define STAGE(T, S)                                                                     \
    do {                                                                                \
      const int k0_ = (T) * 64;                                                         \
      char* Kd_ = asmem + (S) * 32768;                                                  \
      char* Vd_ = Kd_ + 16384;                                                          \
      _Pragma("unroll")                                                                 \
      for (int p = 0; p < 2; p++) {                                                     \
        GLDS16(Kbase + (size_t)(k0_ + p * 32 + trow) * (NKV * HD) + kcol,               \
               Kd_ + (p * 512 + tid) * 16);                                             \
        GLDS16(Vbase + (size_t)(p * 64 + vrow) * S_LEN + k0_ + vcol,                    \
               Vd_ + (p * 512 + tid) * 16);                                             \
      }                                                                                 \
    } while (0)

    STAGE(0, 0);

    for (int t = 0; t < ntiles; t++) {
      __syncthreads();  // drains tile t's staging loads + joins waves
      if (t + 1 < ntiles) STAGE(t + 1, (t + 1) & 1);

      const char* Ksb = asmem + (t & 1) * 32768;
      const char* Vsb = Ksb + 16384;
      const int k0 = t * 64;

      f32x16 s0 = {}, s1 = {};
      {
        const char* kp0 = Ksb + l31 * 256;
        const char* kp1 = kp0 + 32 * 256;
        const int sw = (l31 & 7) << 4;
        __builtin_amdgcn_s_setprio(1);
#pragma unroll
        for (int c = 0; c < 8; c++) {
          const int cb = (c * 32 + hh * 16) ^ sw;
          bf16x8 kf0 = *reinterpret_cast<const bf16x8*>(kp0 + cb);
          s0 = __builtin_amdgcn_mfma_f32_32x32x16_bf16(kf0, qf[c], s0, 0, 0, 0);
          bf16x8 kf1 = *reinterpret_cast<const bf16x8*>(kp1 + cb);
          s1 = __builtin_amdgcn_mfma_f32_32x32x16_bf16(kf1, qf[c], s1, 0, 0, 0);
        }
        __builtin_amdgcn_s_setprio(0);
      }

      if (k0 + 63 > qw) {
#pragma unroll
        for (int r = 0; r < 16; r++) {
          const int kvo = k0 + ((r & 3) + 8 * (r >> 2)) + 4 * hh;
          if (kvo > qg)      s0[r] = -1.0e9f;
          if (kvo + 32 > qg) s1[r] = -1.0e9f;
        }
      }

      float pmax = -3.0e38f;
#pragma unroll
      for (int r = 0; r < 16; r++) { pmax = fmaxf(pmax, s0[r]); pmax = fmaxf(pmax, s1[r]); }
      pmax = fmaxf(pmax, __shfl_xor(pmax, 32));
      if (!__all(pmax <= mrun + 11.5f)) {
        const float mnew = fmaxf(mrun, pmax);
        const float fs = exp2f(mrun - mnew);
        lsum *= fs;
#pragma unroll
        for (int dt = 0; dt < 4; dt++) o[dt] *= fs;
        mrun = mnew;
      }
      float psum = 0.0f;
#pragma unroll
      for (int r = 0; r < 16; r++) {
        s0[r] = exp2f(s0[r] - mrun); psum += s0[r];
        s1[r] = exp2f(s1[r] - mrun); psum += s1[r];
      }
      lsum += psum;

      unsigned int pk[2][8], px[2][8];
#pragma unroll
      for (int jj = 0; jj < 8; jj++) {
        pk[0][jj] = pack2(s0[2 * jj], s0[2 * jj + 1]);
        pk[1][jj] = pack2(s1[2 * jj], s1[2 * jj + 1]);
      }
#pragma unroll
      for (int tt = 0; tt < 2; tt++)
#pragma unroll
        for (int jj = 0; jj < 8; jj++) px[tt][jj] = __shfl_xor(pk[tt][jj], 32);

      __builtin_amdgcn_s_setprio(1);
#pragma unroll
      for (int tt = 0; tt < 2; tt++) {
#pragma unroll
        for (int c2 = 0; c2 < 2; c2++) {
          u32x4 pb4;
          if (hh == 0)
            pb4 = (u32x4){pk[tt][4 * c2], pk[tt][4 * c2 + 1], px[tt][4 * c2], px[tt][4 * c2 + 1]};
          else
            pb4 = (u32x4){px[tt][4 * c2 + 2], px[tt][4 * c2 + 3], pk[tt][4 * c2 + 2], pk[tt][4 * c2 + 3]};
          bf16x8 pbf = __builtin_bit_cast(bf16x8, pb4);
          const int colb = tt * 64 + c2 * 32 + hh * 16;
#pragma unroll
          for (int dt = 0; dt < 4; dt++) {
            const int d = dt * 32 + l31;
            bf16x8 vf = *reinterpret_cast<const bf16x8*>(Vsb + d * 128 + (colb ^ ((d & 7) << 4)));
            o[dt] = __builtin_amdgcn_mfma_f32_32x32x16_bf16(vf, pbf, o[dt], 0, 0, 0);
          }
        }
      }
      __builtin_amdgcn_s_setprio(0);
    }
#undef STAGE

    __syncthreads();  // epilogue scratch spans both slots: wait all tile reads done

    lsum += __shfl_xor(lsum, 32);
    const float inv = 1.0f / lsum;
    char* my = asmem + wid * 8192;  // 8 waves x 8KB = full 64KB
#pragma unroll
    for (int dt = 0; dt < 4; dt++) {
#pragma unroll
      for (int jj = 0; jj < 8; jj++) {
        const int r = 2 * jj;
        const int d = dt * 32 + ((r & 3) + 8 * (r >> 2)) + 4 * hh;
        const unsigned int w = pack2(o[dt][r] * inv, o[dt][r + 1] * inv);
        *reinterpret_cast<unsigned int*>(my + ((l31 * 256 + d * 2) ^ ((l31 & 7) << 4))) = w;
      }
    }
#pragma unroll
    for (int jj = 0; jj < 8; jj++) {
      const int idx = jj * 64 + lane;
      const int row = idx >> 4, c16 = idx & 15;
      u32x4 val = *reinterpret_cast<u32x4*>(my + row * 256 + ((c16 * 16) ^ ((row & 7) << 4)));
      *reinterpret_cast<u32x4*>(Ob + (size_t)(b * S_LEN + qw + row) * (NH * HD) + h * HD + c16 * 8) = val;
    }
  }
}

// ---------------- launch ----------------
extern "C" void kernel_launch(void* const* d_in, const int* in_sizes, int n_in,
                              void* d_out, int out_size, void* d_ws, size_t ws_size,
                              hipStream_t stream) {
  (void)in_sizes; (void)n_in; (void)out_size; (void)ws_size;
  const float* x    = (const float*)d_in[0];
  const float* wq_w = (const float*)d_in[1];
  const float* wq_b = (const float*)d_in[2];
  const float* wk_w = (const float*)d_in[3];
  const float* wk_b = (const float*)d_in[4];
  const float* wv_w = (const float*)d_in[5];
  const float* wv_b = (const float*)d_in[6];
  const float* wo_w = (const float*)d_in[7];
  const float* fcos = (const float*)d_in[10];
  const float* fsin = (const float*)d_in[11];
  const int*   spp  = (const int*)d_in[13];
  float* out = (float*)d_out;

  constexpr size_t XB_N = (size_t)4096 * 3584;
  constexpr size_t WQ_N = (size_t)3584 * 3584;
  constexpr size_t WK_N = (size_t)512 * 3584;
  constexpr size_t WO_N = (size_t)3584 * 3584;
  constexpr size_t KB_N = (size_t)4096 * 512;

  __bf16* xb  = (__bf16*)d_ws;
  __bf16* wqb = xb + XB_N;
  __bf16* wkb = wqb + WQ_N;
  __bf16* wvb = wkb + WK_N;
  __bf16* wob = wvb + WK_N;
  __bf16* Qb  = wob + WO_N;
  __bf16* Kb  = Qb + XB_N;
  __bf16* Vt  = Kb + KB_N;
  int*    ctr = (int*)(Vt + KB_N);
  __bf16* Ob  = xb;  // alias: xb dead after QKV GEMMs (stream-ordered)

  constexpr int N0 = (int)(XB_N / 4), N1 = (int)(WQ_N / 4), N2 = (int)(WK_N / 4),
                N3 = (int)(WK_N / 4), N4 = (int)(WO_N / 4);
  constexpr int NTOT = N0 + N1 + N2 + N3 + N4;
  cvt5_kernel<<<2048, 256, 0, stream>>>(x, wq_w, wk_w, wv_w, wo_w,
                                        xb, wqb, wkb, wvb, wob,
                                        N0, N1, N2, N3, ctr, NTOT);

  gemm256<2><<<dim3(224), 512, 131072, stream>>>(xb, wqb, wq_b, Qb, 4096, 3584, 3584,
                                                 fcos, fsin, spp, SCALE_LOG2);
  gemm_kv<<<dim3(8, 32), 256, 0, stream>>>(xb, wkb, wk_b, Kb, wvb, wv_b, Vt,
                                           fcos, fsin, spp);
  attn_kernel<<<dim3(512), 512, 0, stream>>>(Qb, Kb, Vt, Ob, ctr);
  gemm256<0><<<dim3(224), 512, 131072, stream>>>(Ob, wob, nullptr, out, 4096, 3584, 3584,
                                                 nullptr, nullptr, nullptr, 1.0f);
}

// Round 15
// 426.992 us; speedup vs baseline: 1.6976x; 1.6976x over previous
//
#include <hip/hip_runtime.h>
#include <hip/hip_bf16.h>

typedef __attribute__((ext_vector_type(4)))  float  f32x4;
typedef __attribute__((ext_vector_type(16))) float  f32x16;
typedef __attribute__((ext_vector_type(8)))  __bf16 bf16x8;
typedef __attribute__((ext_vector_type(4)))  __bf16 bf16x4;
typedef __attribute__((ext_vector_type(4)))  unsigned int u32x4;

constexpr int S_LEN = 2048, DMODEL = 3584, NH = 28, NKV = 4, HD = 128, NREP = 7;
// 128^-0.5 * log2(e): softmax computed in base-2 (exp2f == bare v_exp_f32)
constexpr float SCALE_LOG2 = 0.1275174331f;

__device__ __forceinline__ unsigned int pack2(float a, float b) {
  unsigned short ua = __builtin_bit_cast(unsigned short, (__bf16)a);
  unsigned short ub = __builtin_bit_cast(unsigned short, (__bf16)b);
  return (unsigned int)ua | ((unsigned int)ub << 16);
}

// ---------------- fused f32 -> bf16 convert (5 tensors) + ctr zero ----------------
__global__ void cvt5_kernel(const float* __restrict__ s0, const float* __restrict__ s1,
                            const float* __restrict__ s2, const float* __restrict__ s3,
                            const float* __restrict__ s4,
                            __bf16* __restrict__ d0, __bf16* __restrict__ d1,
                            __bf16* __restrict__ d2, __bf16* __restrict__ d3,
                            __bf16* __restrict__ d4,
                            int n0, int n1, int n2, int n3, int* __restrict__ ctr, int total) {
  if (blockIdx.x == 0 && threadIdx.x == 0) *ctr = 0;
  for (int i = blockIdx.x * blockDim.x + threadIdx.x; i < total; i += gridDim.x * blockDim.x) {
    const float* s; __bf16* d; int j = i;
    if (j < n0) { s = s0; d = d0; }
    else { j -= n0;
      if (j < n1) { s = s1; d = d1; }
      else { j -= n1;
        if (j < n2) { s = s2; d = d2; }
        else { j -= n2;
          if (j < n3) { s = s3; d = d3; }
          else { j -= n3; s = s4; d = d4; }
        }
      }
    }
    float4 v = reinterpret_cast<const float4*>(s)[j];
    bf16x4 o;
    o[0] = (__bf16)v.x; o[1] = (__bf16)v.y; o[2] = (__bf16)v.z; o[3] = (__bf16)v.w;
    reinterpret_cast<bf16x4*>(d)[j] = o;
  }
}

#define GLDS16(gsrc, ldst)                                                              \
  __builtin_amdgcn_global_load_lds((const __attribute__((address_space(1))) void*)(gsrc),\
                                   (__attribute__((address_space(3))) void*)(ldst), 16, 0, 0)

// ============ 256x256 GEMM: R6 loop + B-fragment one-ahead prefetch ============
template <int MODE>
__global__ __launch_bounds__(512, 2) void gemm256(
    const __bf16* __restrict__ A, const __bf16* __restrict__ Bw,
    const float* __restrict__ bias, void* __restrict__ Cout,
    int M, int N, int K,
    const float* __restrict__ fcos, const float* __restrict__ fsin,
    const int* __restrict__ sp_ptr, float scale)
{
  extern __shared__ char smem[];  // [0,64K): A slots[4][16K]; [64K,128K): B slots[4][16K]
  const int tid = threadIdx.x;
  const int lane = tid & 63, wid = tid >> 6;
  const int wm = wid >> 2, wn = wid & 3;
  const int l15 = lane & 15, g = (lane >> 4) & 3;

  const int chunk = gridDim.x >> 3;
  const int wg = (blockIdx.x & 7) * chunk + (blockIdx.x >> 3);
  const int nbx = N >> 8;
  const int by = wg / nbx, bx = wg % nbx;
  const int row0 = by * 256, col0 = bx * 256;

  const int srL   = 16 * (tid >> 6) + ((tid >> 2) & 15);
  const int cperm = ((tid & 3) * 8) ^ (((tid >> 5) & 1) * 16);
  const __bf16* pA0 = A + (size_t)(row0 + srL) * K + cperm;
  const __bf16* pA1 = pA0 + (size_t)128 * K;
  const __bf16* pB0 = Bw + (size_t)(col0 + srL) * K + cperm;
  const __bf16* pB1 = pB0 + (size_t)128 * K;
  char* ldsA = smem + tid * 16;
  char* ldsB = smem + 65536 + tid * 16;

  const int sw = ((l15 >> 3) & 1) << 5;
  const int aoff = wm * 8192 + l15 * 64 + ((g * 16) ^ sw);
  const int boff = 65536 + wn * 4096 + l15 * 64 + ((g * 16) ^ sw);

  f32x4 acc[8][4] = {};
  const int nt = K >> 5;  // 112 (even)
  bf16x8 bE[4], bO[4];

#pragma unroll
  for (int pt = 0; pt < 3; pt++) {
    const size_t ko = (size_t)pt * 32;
    char* sA = ldsA + pt * 16384;
    char* sB = ldsB + pt * 16384;
    GLDS16(pA0 + ko, sA);
    GLDS16(pA1 + ko, sA + 8192);
    GLDS16(pB0 + ko, sB);
    GLDS16(pB1 + ko, sB + 8192);
  }
  asm volatile("s_waitcnt vmcnt(4)" ::: "memory");   // batches 0,1 resident
  __builtin_amdgcn_s_barrier();
  __builtin_amdgcn_sched_barrier(0);
  {
    const char* sb0 = smem + boff;  // slot 0
#pragma unroll
    for (int fn = 0; fn < 4; fn++)
      bE[fn] = *reinterpret_cast<const bf16x8*>(sb0 + fn * 1024);
  }

#define GTILE(T, BC, BN)                                                                \
  do {                                                                                  \
    const char* sa = smem + ((T) & 3) * 16384 + aoff;                                   \
    bf16x8 a0[4], a1[4];                                                                \
    _Pragma("unroll")                                                                   \
    for (int fm = 0; fm < 4; fm++)                                                      \
      a0[fm] = *reinterpret_cast<const bf16x8*>(sa + fm * 1024);                        \
    _Pragma("unroll")                                                                   \
    for (int fm = 0; fm < 4; fm++)                                                      \
      a1[fm] = *reinterpret_cast<const bf16x8*>(sa + (4 + fm) * 1024);                  \
    const bool hasnext = (T) + 1 < nt;                                                  \
    if (hasnext) {                                                                      \
      const char* sbn = smem + (((T) + 1) & 3) * 16384 + boff;                          \
      _Pragma("unroll")                                                                 \
      for (int fn = 0; fn < 4; fn++)                                                    \
        BN[fn] = *reinterpret_cast<const bf16x8*>(sbn + fn * 1024);                     \
    }                                                                                   \
    if ((T) + 3 < nt) {                                                                 \
      const size_t ko = (size_t)((T) + 3) * 32;                                         \
      char* sA = ldsA + (((T) + 3) & 3) * 16384;                                        \
      char* sB = ldsB + (((T) + 3) & 3) * 16384;                                        \
      GLDS16(pA0 + ko, sA);                                                             \
      GLDS16(pA1 + ko, sA + 8192);                                                      \
      GLDS16(pB0 + ko, sB);                                                             \
      GLDS16(pB1 + ko, sB + 8192);                                                      \
    }                                                                                   \
    asm volatile("s_waitcnt lgkmcnt(8)" ::: "memory");                                  \
    __builtin_amdgcn_sched_barrier(0);                                                  \
    __builtin_amdgcn_s_setprio(1);                                                      \
    _Pragma("unroll")                                                                   \
    for (int fn = 0; fn < 4; fn++)                                                      \
      _Pragma("unroll")                                                                 \
      for (int fm = 0; fm < 4; fm++)                                                    \
        acc[fm][fn] = __builtin_amdgcn_mfma_f32_16x16x32_bf16(a0[fm], BC[fn],           \
                                                              acc[fm][fn], 0, 0, 0);   \
    __builtin_amdgcn_s_setprio(0);                                                      \
    if (hasnext) asm volatile("s_waitcnt lgkmcnt(4)" ::: "memory");                     \
    else         asm volatile("s_waitcnt lgkmcnt(0)" ::: "memory");                     \
    __builtin_amdgcn_sched_barrier(0);                                                  \
    __builtin_amdgcn_s_setprio(1);                                                      \
    _Pragma("unroll")                                                                   \
    for (int fn = 0; fn < 4; fn++)                                                      \
      _Pragma("unroll")                                                                 \
      for (int fm = 0; fm < 4; fm++)                                                    \
        acc[4 + fm][fn] = __builtin_amdgcn_mfma_f32_16x16x32_bf16(a1[fm], BC[fn],       \
                                                                  acc[4 + fm][fn],     \
                                                                  0, 0, 0);            \
    __builtin_amdgcn_s_setprio(0);                                                      \
    if ((T) < nt - 3) asm volatile("s_waitcnt vmcnt(4)" ::: "memory");                  \
    else              asm volatile("s_waitcnt vmcnt(0)" ::: "memory");                  \
    __builtin_amdgcn_s_barrier();                                                       \
    __builtin_amdgcn_sched_barrier(0);                                                  \
  } while (0)

  for (int t = 0; t < nt; t += 2) {
    GTILE(t, bE, bO);
    GTILE(t + 1, bO, bE);
  }
#undef GTILE

  if constexpr (MODE == 0) {
    float* C = (float*)Cout;
#pragma unroll
    for (int fm = 0; fm < 8; fm++) {
      const int row = row0 + wm * 128 + fm * 16 + 4 * g;
#pragma unroll
      for (int fn = 0; fn < 4; fn++) {
        const int col = col0 + wn * 64 + fn * 16 + l15;
#pragma unroll
        for (int r = 0; r < 4; r++)
          C[(size_t)(row + r) * N + col] = acc[fm][fn][r];
      }
    }
  } else {
    __bf16* C = (__bf16*)Cout;
    const int sp = sp_ptr[0];
    float bval[4];
#pragma unroll
    for (int fn = 0; fn < 4; fn++) bval[fn] = bias[col0 + wn * 64 + fn * 16 + l15];
#pragma unroll
    for (int fm = 0; fm < 8; fm++) {
#pragma unroll
      for (int fn = 0; fn < 4; fn++) {
        const int col = col0 + wn * 64 + fn * 16 + l15;
        const int i = (col & (HD - 1)) >> 1;
#pragma unroll
        for (int r = 0; r < 4; r++) {
          const int row = row0 + wm * 128 + fm * 16 + 4 * g + r;
          float y = acc[fm][fn][r] + bval[fn];
          float p = __shfl_xor(y, 1);
          const int spos = sp + (row & (S_LEN - 1));
          const float c = fcos[spos * (HD / 2) + i];
          const float sn = fsin[spos * (HD / 2) + i];
          y = (col & 1) ? (p * sn + y * c) : (y * c - p * sn);
          C[(size_t)row * N + col] = (__bf16)(y * scale);
        }
      }
    }
  }
}

// ------- fused K+V projection GEMM; V written DIRECTLY transposed to Vt -------
__global__ __launch_bounds__(256) void gemm_kv(
    const __bf16* __restrict__ A,
    const __bf16* __restrict__ Wk, const float* __restrict__ bk, __bf16* __restrict__ Ko,
    const __bf16* __restrict__ Wv, const float* __restrict__ bv, __bf16* __restrict__ Vt,
    const float* __restrict__ fcos, const float* __restrict__ fsin,
    const int* __restrict__ sp_ptr)
{
  constexpr int N = 512, K = 3584;
  __shared__ __bf16 As[128 * 32];
  __shared__ __bf16 Bs[128 * 32];
  const int tid = threadIdx.x;
  const int lane = tid & 63, wid = tid >> 6;
  const int l15 = lane & 15, g = lane >> 4;
  const int wr = wid >> 1, wc = wid & 1;
  const bool isK = blockIdx.x < 4;
  const __bf16* Bw = isK ? Wk : Wv;
  const float* bias = isK ? bk : bv;
  const int row0 = blockIdx.y * 128;
  const int col0 = (blockIdx.x & 3) * 128;

  f32x4 acc[4][4] = {};

  const int srow = tid >> 2;
  const int scol = (tid & 3) * 8;
  const __bf16* Ag0 = A + (size_t)(row0 + srow) * K + scol;
  const __bf16* Ag1 = Ag0 + (size_t)64 * K;
  const __bf16* Bg0 = Bw + (size_t)(col0 + srow) * K + scol;
  const __bf16* Bg1 = Bg0 + (size_t)64 * K;
  __bf16* As0 = As + tid * 8;
  __bf16* As1 = As + 2048 + tid * 8;
  __bf16* Bs0 = Bs + tid * 8;
  __bf16* Bs1 = Bs + 2048 + tid * 8;

  for (int k0 = 0; k0 < K; k0 += 32) {
    GLDS16(Ag0 + k0, As0);
    GLDS16(Ag1 + k0, As1);
    GLDS16(Bg0 + k0, Bs0);
    GLDS16(Bg1 + k0, Bs1);
    __syncthreads();
    bf16x8 af[4], bfr[4];
#pragma unroll
    for (int m = 0; m < 4; m++)
      af[m] = *reinterpret_cast<const bf16x8*>(As + (wr * 64 + m * 16 + l15) * 32 + g * 8);
#pragma unroll
    for (int n = 0; n < 4; n++)
      bfr[n] = *reinterpret_cast<const bf16x8*>(Bs + (wc * 64 + n * 16 + l15) * 32 + g * 8);
#pragma unroll
    for (int m = 0; m < 4; m++)
#pragma unroll
      for (int n = 0; n < 4; n++)
        acc[m][n] = __builtin_amdgcn_mfma_f32_16x16x32_bf16(af[m], bfr[n], acc[m][n], 0, 0, 0);
    __syncthreads();
  }

  const int sp = sp_ptr[0];
  if (isK) {
#pragma unroll
    for (int m = 0; m < 4; m++) {
#pragma unroll
      for (int n = 0; n < 4; n++) {
        const int col = col0 + wc * 64 + n * 16 + l15;
        const float bval = bias[col];
        f32x4 v = acc[m][n];
#pragma unroll
        for (int r = 0; r < 4; r++) {
          const int row = row0 + wr * 64 + m * 16 + 4 * g + r;
          float y = v[r] + bval;
          float p = __shfl_xor(y, 1);
          const int i = (col & (HD - 1)) >> 1;
          const int spos = sp + (row & (S_LEN - 1));
          const float c = fcos[spos * (HD / 2) + i];
          const float sn = fsin[spos * (HD / 2) + i];
          y = (col & 1) ? (p * sn + y * c) : (y * c - p * sn);
          Ko[(size_t)row * N + col] = (__bf16)y;
        }
      }
    }
  } else {
    const int b4kv = ((row0 >> 11) * 4) + (blockIdx.x & 3);
    __bf16* vbase = Vt + ((size_t)b4kv << 18);  // 128*2048
#pragma unroll
    for (int m = 0; m < 4; m++) {
#pragma unroll
      for (int n = 0; n < 4; n++) {
        const int d = wc * 64 + n * 16 + l15;
        const float bval = bias[col0 + d];
        const int s0 = (row0 + wr * 64 + m * 16 + 4 * g) & (S_LEN - 1);
        f32x4 v = acc[m][n];
        bf16x4 o;
#pragma unroll
        for (int r = 0; r < 4; r++) o[r] = (__bf16)(v[r] + bval);
        *reinterpret_cast<bf16x4*>(vbase + (size_t)d * S_LEN + s0) = o;
      }
    }
  }
}

// -------- Flash attention: 8-wave blocks (512 thr), K/V tile shared by 256 q-rows,
// persistent blocks + LPT dynamic queue, double-buffered K/V.
// launch_bounds(512,2): VGPR cap 256 (no spill); LDS 64KB -> 2 blocks/CU -> 16 waves/CU.
__global__ __launch_bounds__(512, 2) void attn_kernel(
    const __bf16* __restrict__ Qb, const __bf16* __restrict__ Kb,
    const __bf16* __restrict__ Vt, __bf16* __restrict__ Ob, int* __restrict__ ctr)
{
  __shared__ __align__(16) char asmem[65536];
  __shared__ int jsh;

  const int tid = threadIdx.x, lane = tid & 63, wid = tid >> 6;  // wid 0..7
  const int l31 = lane & 31, hh = lane >> 5;

  // staging maps (512 threads): K [64][128] in 2 passes of 32 rows;
  // V [128][64] in 2 passes of 64 rows. Pre-swizzled source, linear dest (rule 21).
  const int trow = tid >> 4;                                   // 0..31
  const int kcol = (((tid & 15) * 16) ^ ((trow & 7) << 4)) >> 1;
  const int vrow = tid >> 3;                                   // 0..63
  const int vcol = (((tid & 7) * 16) ^ ((vrow & 7) << 4)) >> 1;

  constexpr int NITEMS = 8 * NH * 2;  // 448 (8 q-blocks of 256 rows)

  while (true) {
    if (tid == 0) jsh = atomicAdd(ctr, 1);
    __syncthreads();  // broadcast jsh + fences prev epilogue LDS reads vs STAGE(0)
    const int j = jsh;
    if (j >= NITEMS) break;

    const int qi = 7 - (j / 56);         // q-block (256 rows), LPT descending
    const int r56 = j % 56;
    const int h = r56 >> 1, b = r56 & 1;
    const int kvh = h / NREP;
    const int qw = qi * 256 + wid * 32;  // wave's first q row
    const int qg = qw + l31;

    const __bf16* Kbase = Kb + ((size_t)b * S_LEN * NKV + kvh) * HD;
    const __bf16* Vbase = Vt + ((size_t)b * NKV + kvh) * (size_t)HD * S_LEN;

    bf16x8 qf[8];
    {
      const __bf16* qp = Qb + (((size_t)b * S_LEN + qg) * NH + h) * HD + hh * 8;
#pragma unroll
      for (int c = 0; c < 8; c++) qf[c] = *reinterpret_cast<const bf16x8*>(qp + c * 16);
    }

    f32x16 o[4] = {};
    float mrun = -3.0e38f, lsum = 0.0f;

    const int ntiles = 4 * qi + 4;  // even -> last tile reads slot 1

#define STAGE(T, S)                                                                     \
    do {                                                                                \
      const int k0_ = (T) * 64;                                                         \
      char* Kd_ = asmem + (S) * 32768;                                                  \
      char* Vd_ = Kd_ + 16384;                                                          \
      _Pragma("unroll")                                                                 \
      for (int p = 0; p < 2; p++) {                                                     \
        GLDS16(Kbase + (size_t)(k0_ + p * 32 + trow) * (NKV * HD) + kcol,               \
               Kd_ + (p * 512 + tid) * 16);                                             \
        GLDS16(Vbase + (size_t)(p * 64 + vrow) * S_LEN + k0_ + vcol,                    \
               Vd_ + (p * 512 + tid) * 16);                                             \
      }                                                                                 \
    } while (0)

    STAGE(0, 0);

    for (int t = 0; t < ntiles; t++) {
      __syncthreads();  // drains tile t's staging loads + joins waves
      if (t + 1 < ntiles) STAGE(t + 1, (t + 1) & 1);

      const char* Ksb = asmem + (t & 1) * 32768;
      const char* Vsb = Ksb + 16384;
      const int k0 = t * 64;

      f32x16 s0 = {}, s1 = {};
      {
        const char* kp0 = Ksb + l31 * 256;
        const char* kp1 = kp0 + 32 * 256;
        const int sw = (l31 & 7) << 4;
        __builtin_amdgcn_s_setprio(1);
#pragma unroll
        for (int c = 0; c < 8; c++) {
          const int cb = (c * 32 + hh * 16) ^ sw;
          bf16x8 kf0 = *reinterpret_cast<const bf16x8*>(kp0 + cb);
          s0 = __builtin_amdgcn_mfma_f32_32x32x16_bf16(kf0, qf[c], s0, 0, 0, 0);
          bf16x8 kf1 = *reinterpret_cast<const bf16x8*>(kp1 + cb);
          s1 = __builtin_amdgcn_mfma_f32_32x32x16_bf16(kf1, qf[c], s1, 0, 0, 0);
        }
        __builtin_amdgcn_s_setprio(0);
      }

      if (k0 + 63 > qw) {
#pragma unroll
        for (int r = 0; r < 16; r++) {
          const int kvo = k0 + ((r & 3) + 8 * (r >> 2)) + 4 * hh;
          if (kvo > qg)      s0[r] = -1.0e9f;
          if (kvo + 32 > qg) s1[r] = -1.0e9f;
        }
      }

      float pmax = -3.0e38f;
#pragma unroll
      for (int r = 0; r < 16; r++) { pmax = fmaxf(pmax, s0[r]); pmax = fmaxf(pmax, s1[r]); }
      pmax = fmaxf(pmax, __shfl_xor(pmax, 32));
      if (!__all(pmax <= mrun + 11.5f)) {
        const float mnew = fmaxf(mrun, pmax);
        const float fs = exp2f(mrun - mnew);
        lsum *= fs;
#pragma unroll
        for (int dt = 0; dt < 4; dt++) o[dt] *= fs;
        mrun = mnew;
      }
      float psum = 0.0f;
#pragma unroll
      for (int r = 0; r < 16; r++) {
        s0[r] = exp2f(s0[r] - mrun); psum += s0[r];
        s1[r] = exp2f(s1[r] - mrun); psum += s1[r];
      }
      lsum += psum;

      unsigned int pk[2][8], px[2][8];
#pragma unroll
      for (int jj = 0; jj < 8; jj++) {
        pk[0][jj] = pack2(s0[2 * jj], s0[2 * jj + 1]);
        pk[1][jj] = pack2(s1[2 * jj], s1[2 * jj + 1]);
      }
#pragma unroll
      for (int tt = 0; tt < 2; tt++)
#pragma unroll
        for (int jj = 0; jj < 8; jj++) px[tt][jj] = __shfl_xor(pk[tt][jj], 32);

      __builtin_amdgcn_s_setprio(1);
#pragma unroll
      for (int tt = 0; tt < 2; tt++) {
#pragma unroll
        for (int c2 = 0; c2 < 2; c2++) {
          u32x4 pb4;
          if (hh == 0)
            pb4 = (u32x4){pk[tt][4 * c2], pk[tt][4 * c2 + 1], px[tt][4 * c2], px[tt][4 * c2 + 1]};
          else
            pb4 = (u32x4){px[tt][4 * c2 + 2], px[tt][4 * c2 + 3], pk[tt][4 * c2 + 2], pk[tt][4 * c2 + 3]};
          bf16x8 pbf = __builtin_bit_cast(bf16x8, pb4);
          const int colb = tt * 64 + c2 * 32 + hh * 16;
#pragma unroll
          for (int dt = 0; dt < 4; dt++) {
            const int d = dt * 32 + l31;
            bf16x8 vf = *reinterpret_cast<const bf16x8*>(Vsb + d * 128 + (colb ^ ((d & 7) << 4)));
            o[dt] = __builtin_amdgcn_mfma_f32_32x32x16_bf16(vf, pbf, o[dt], 0, 0, 0);
          }
        }
      }
      __builtin_amdgcn_s_setprio(0);
    }
#undef STAGE

    __syncthreads();  // epilogue scratch spans both slots: wait all tile reads done

    lsum += __shfl_xor(lsum, 32);
    const float inv = 1.0f / lsum;
    char* my = asmem + wid * 8192;  // 8 waves x 8KB = full 64KB
#pragma unroll
    for (int dt = 0; dt < 4; dt++) {
#pragma unroll
      for (int jj = 0; jj < 8; jj++) {
        const int r = 2 * jj;
        const int d = dt * 32 + ((r & 3) + 8 * (r >> 2)) + 4 * hh;
        const unsigned int w = pack2(o[dt][r] * inv, o[dt][r + 1] * inv);
        *reinterpret_cast<unsigned int*>(my + ((l31 * 256 + d * 2) ^ ((l31 & 7) << 4))) = w;
      }
    }
#pragma unroll
    for (int jj = 0; jj < 8; jj++) {
      const int idx = jj * 64 + lane;
      const int row = idx >> 4, c16 = idx & 15;
      u32x4 val = *reinterpret_cast<u32x4*>(my + row * 256 + ((c16 * 16) ^ ((row & 7) << 4)));
      *reinterpret_cast<u32x4*>(Ob + (size_t)(b * S_LEN + qw + row) * (NH * HD) + h * HD + c16 * 8) = val;
    }
  }
}

// ---------------- launch ----------------
extern "C" void kernel_launch(void* const* d_in, const int* in_sizes, int n_in,
                              void* d_out, int out_size, void* d_ws, size_t ws_size,
                              hipStream_t stream) {
  (void)in_sizes; (void)n_in; (void)out_size; (void)ws_size;
  const float* x    = (const float*)d_in[0];
  const float* wq_w = (const float*)d_in[1];
  const float* wq_b = (const float*)d_in[2];
  const float* wk_w = (const float*)d_in[3];
  const float* wk_b = (const float*)d_in[4];
  const float* wv_w = (const float*)d_in[5];
  const float* wv_b = (const float*)d_in[6];
  const float* wo_w = (const float*)d_in[7];
  const float* fcos = (const float*)d_in[10];
  const float* fsin = (const float*)d_in[11];
  const int*   spp  = (const int*)d_in[13];
  float* out = (float*)d_out;

  constexpr size_t XB_N = (size_t)4096 * 3584;
  constexpr size_t WQ_N = (size_t)3584 * 3584;
  constexpr size_t WK_N = (size_t)512 * 3584;
  constexpr size_t WO_N = (size_t)3584 * 3584;
  constexpr size_t KB_N = (size_t)4096 * 512;

  __bf16* xb  = (__bf16*)d_ws;
  __bf16* wqb = xb + XB_N;
  __bf16* wkb = wqb + WQ_N;
  __bf16* wvb = wkb + WK_N;
  __bf16* wob = wvb + WK_N;
  __bf16* Qb  = wob + WO_N;
  __bf16* Kb  = Qb + XB_N;
  __bf16* Vt  = Kb + KB_N;
  int*    ctr = (int*)(Vt + KB_N);
  __bf16* Ob  = xb;  // alias: xb dead after QKV GEMMs (stream-ordered)

  constexpr int N0 = (int)(XB_N / 4), N1 = (int)(WQ_N / 4), N2 = (int)(WK_N / 4),
                N3 = (int)(WK_N / 4), N4 = (int)(WO_N / 4);
  constexpr int NTOT = N0 + N1 + N2 + N3 + N4;
  cvt5_kernel<<<2048, 256, 0, stream>>>(x, wq_w, wk_w, wv_w, wo_w,
                                        xb, wqb, wkb, wvb, wob,
                                        N0, N1, N2, N3, ctr, NTOT);

  gemm256<2><<<dim3(224), 512, 131072, stream>>>(xb, wqb, wq_b, Qb, 4096, 3584, 3584,
                                                 fcos, fsin, spp, SCALE_LOG2);
  gemm_kv<<<dim3(8, 32), 256, 0, stream>>>(xb, wkb, wk_b, Kb, wvb, wv_b, Vt,
                                           fcos, fsin, spp);
  attn_kernel<<<dim3(448), 512, 0, stream>>>(Qb, Kb, Vt, Ob, ctr);
  gemm256<0><<<dim3(224), 512, 131072, stream>>>(Ob, wob, nullptr, out, 4096, 3584, 3584,
                                                 nullptr, nullptr, nullptr, 1.0f);
}

// Round 16
// 421.283 us; speedup vs baseline: 1.7206x; 1.0136x over previous
//
#include <hip/hip_runtime.h>
#include <hip/hip_bf16.h>

typedef __attribute__((ext_vector_type(4)))  float  f32x4;
typedef __attribute__((ext_vector_type(16))) float  f32x16;
typedef __attribute__((ext_vector_type(8)))  __bf16 bf16x8;
typedef __attribute__((ext_vector_type(4)))  __bf16 bf16x4;
typedef __attribute__((ext_vector_type(4)))  unsigned int u32x4;

constexpr int S_LEN = 2048, DMODEL = 3584, NH = 28, NKV = 4, HD = 128, NREP = 7;
// 128^-0.5 * log2(e): softmax computed in base-2 (exp2f == bare v_exp_f32)
constexpr float SCALE_LOG2 = 0.1275174331f;

__device__ __forceinline__ unsigned int pack2(float a, float b) {
  unsigned short ua = __builtin_bit_cast(unsigned short, (__bf16)a);
  unsigned short ub = __builtin_bit_cast(unsigned short, (__bf16)b);
  return (unsigned int)ua | ((unsigned int)ub << 16);
}

// ---------------- fused f32 -> bf16 convert (5 tensors) + ctr zero ----------------
__global__ void cvt5_kernel(const float* __restrict__ s0, const float* __restrict__ s1,
                            const float* __restrict__ s2, const float* __restrict__ s3,
                            const float* __restrict__ s4,
                            __bf16* __restrict__ d0, __bf16* __restrict__ d1,
                            __bf16* __restrict__ d2, __bf16* __restrict__ d3,
                            __bf16* __restrict__ d4,
                            int n0, int n1, int n2, int n3, int* __restrict__ ctr, int total) {
  if (blockIdx.x == 0 && threadIdx.x == 0) *ctr = 0;
  for (int i = blockIdx.x * blockDim.x + threadIdx.x; i < total; i += gridDim.x * blockDim.x) {
    const float* s; __bf16* d; int j = i;
    if (j < n0) { s = s0; d = d0; }
    else { j -= n0;
      if (j < n1) { s = s1; d = d1; }
      else { j -= n1;
        if (j < n2) { s = s2; d = d2; }
        else { j -= n2;
          if (j < n3) { s = s3; d = d3; }
          else { j -= n3; s = s4; d = d4; }
        }
      }
    }
    float4 v = reinterpret_cast<const float4*>(s)[j];
    bf16x4 o;
    o[0] = (__bf16)v.x; o[1] = (__bf16)v.y; o[2] = (__bf16)v.z; o[3] = (__bf16)v.w;
    reinterpret_cast<bf16x4*>(d)[j] = o;
  }
}

#define GLDS16(gsrc, ldst)                                                              \
  __builtin_amdgcn_global_load_lds((const __attribute__((address_space(1))) void*)(gsrc),\
                                   (__attribute__((address_space(3))) void*)(ldst), 16, 0, 0)

// ============ 256x256 GEMM: R6 loop + B-fragment one-ahead prefetch ============
template <int MODE>
__global__ __launch_bounds__(512, 2) void gemm256(
    const __bf16* __restrict__ A, const __bf16* __restrict__ Bw,
    const float* __restrict__ bias, void* __restrict__ Cout,
    int M, int N, int K,
    const float* __restrict__ fcos, const float* __restrict__ fsin,
    const int* __restrict__ sp_ptr, float scale)
{
  extern __shared__ char smem[];  // [0,64K): A slots[4][16K]; [64K,128K): B slots[4][16K]
  const int tid = threadIdx.x;
  const int lane = tid & 63, wid = tid >> 6;
  const int wm = wid >> 2, wn = wid & 3;
  const int l15 = lane & 15, g = (lane >> 4) & 3;

  const int chunk = gridDim.x >> 3;
  const int wg = (blockIdx.x & 7) * chunk + (blockIdx.x >> 3);
  const int nbx = N >> 8;
  const int by = wg / nbx, bx = wg % nbx;
  const int row0 = by * 256, col0 = bx * 256;

  const int srL   = 16 * (tid >> 6) + ((tid >> 2) & 15);
  const int cperm = ((tid & 3) * 8) ^ (((tid >> 5) & 1) * 16);
  const __bf16* pA0 = A + (size_t)(row0 + srL) * K + cperm;
  const __bf16* pA1 = pA0 + (size_t)128 * K;
  const __bf16* pB0 = Bw + (size_t)(col0 + srL) * K + cperm;
  const __bf16* pB1 = pB0 + (size_t)128 * K;
  char* ldsA = smem + tid * 16;
  char* ldsB = smem + 65536 + tid * 16;

  const int sw = ((l15 >> 3) & 1) << 5;
  const int aoff = wm * 8192 + l15 * 64 + ((g * 16) ^ sw);
  const int boff = 65536 + wn * 4096 + l15 * 64 + ((g * 16) ^ sw);

  f32x4 acc[8][4] = {};
  const int nt = K >> 5;  // 112 (even)
  bf16x8 bE[4], bO[4];

#pragma unroll
  for (int pt = 0; pt < 3; pt++) {
    const size_t ko = (size_t)pt * 32;
    char* sA = ldsA + pt * 16384;
    char* sB = ldsB + pt * 16384;
    GLDS16(pA0 + ko, sA);
    GLDS16(pA1 + ko, sA + 8192);
    GLDS16(pB0 + ko, sB);
    GLDS16(pB1 + ko, sB + 8192);
  }
  asm volatile("s_waitcnt vmcnt(4)" ::: "memory");   // batches 0,1 resident
  __builtin_amdgcn_s_barrier();
  __builtin_amdgcn_sched_barrier(0);
  {
    const char* sb0 = smem + boff;  // slot 0
#pragma unroll
    for (int fn = 0; fn < 4; fn++)
      bE[fn] = *reinterpret_cast<const bf16x8*>(sb0 + fn * 1024);
  }

#define GTILE(T, BC, BN)                                                                \
  do {                                                                                  \
    const char* sa = smem + ((T) & 3) * 16384 + aoff;                                   \
    bf16x8 a0[4], a1[4];                                                                \
    _Pragma("unroll")                                                                   \
    for (int fm = 0; fm < 4; fm++)                                                      \
      a0[fm] = *reinterpret_cast<const bf16x8*>(sa + fm * 1024);                        \
    _Pragma("unroll")                                                                   \
    for (int fm = 0; fm < 4; fm++)                                                      \
      a1[fm] = *reinterpret_cast<const bf16x8*>(sa + (4 + fm) * 1024);                  \
    const bool hasnext = (T) + 1 < nt;                                                  \
    if (hasnext) {                                                                      \
      const char* sbn = smem + (((T) + 1) & 3) * 16384 + boff;                          \
      _Pragma("unroll")                                                                 \
      for (int fn = 0; fn < 4; fn++)                                                    \
        BN[fn] = *reinterpret_cast<const bf16x8*>(sbn + fn * 1024);                     \
    }                                                                                   \
    if ((T) + 3 < nt) {                                                                 \
      const size_t ko = (size_t)((T) + 3) * 32;                                         \
      char* sA = ldsA + (((T) + 3) & 3) * 16384;                                        \
      char* sB = ldsB + (((T) + 3) & 3) * 16384;                                        \
      GLDS16(pA0 + ko, sA);                                                             \
      GLDS16(pA1 + ko, sA + 8192);                                                      \
      GLDS16(pB0 + ko, sB);                                                             \
      GLDS16(pB1 + ko, sB + 8192);                                                      \
    }                                                                                   \
    asm volatile("s_waitcnt lgkmcnt(8)" ::: "memory");                                  \
    __builtin_amdgcn_sched_barrier(0);                                                  \
    __builtin_amdgcn_s_setprio(1);                                                      \
    _Pragma("unroll")                                                                   \
    for (int fn = 0; fn < 4; fn++)                                                      \
      _Pragma("unroll")                                                                 \
      for (int fm = 0; fm < 4; fm++)                                                    \
        acc[fm][fn] = __builtin_amdgcn_mfma_f32_16x16x32_bf16(a0[fm], BC[fn],           \
                                                              acc[fm][fn], 0, 0, 0);   \
    __builtin_amdgcn_s_setprio(0);                                                      \
    if (hasnext) asm volatile("s_waitcnt lgkmcnt(4)" ::: "memory");                     \
    else         asm volatile("s_waitcnt lgkmcnt(0)" ::: "memory");                     \
    __builtin_amdgcn_sched_barrier(0);                                                  \
    __builtin_amdgcn_s_setprio(1);                                                      \
    _Pragma("unroll")                                                                   \
    for (int fn = 0; fn < 4; fn++)                                                      \
      _Pragma("unroll")                                                                 \
      for (int fm = 0; fm < 4; fm++)                                                    \
        acc[4 + fm][fn] = __builtin_amdgcn_mfma_f32_16x16x32_bf16(a1[fm], BC[fn],       \
                                                                  acc[4 + fm][fn],     \
                                                                  0, 0, 0);            \
    __builtin_amdgcn_s_setprio(0);                                                      \
    if ((T) < nt - 3) asm volatile("s_waitcnt vmcnt(4)" ::: "memory");                  \
    else              asm volatile("s_waitcnt vmcnt(0)" ::: "memory");                  \
    __builtin_amdgcn_s_barrier();                                                       \
    __builtin_amdgcn_sched_barrier(0);                                                  \
  } while (0)

  for (int t = 0; t < nt; t += 2) {
    GTILE(t, bE, bO);
    GTILE(t + 1, bO, bE);
  }
#undef GTILE

  if constexpr (MODE == 0) {
    float* C = (float*)Cout;
#pragma unroll
    for (int fm = 0; fm < 8; fm++) {
      const int row = row0 + wm * 128 + fm * 16 + 4 * g;
#pragma unroll
      for (int fn = 0; fn < 4; fn++) {
        const int col = col0 + wn * 64 + fn * 16 + l15;
#pragma unroll
        for (int r = 0; r < 4; r++)
          C[(size_t)(row + r) * N + col] = acc[fm][fn][r];
      }
    }
  } else {
    __bf16* C = (__bf16*)Cout;
    const int sp = sp_ptr[0];
    float bval[4];
#pragma unroll
    for (int fn = 0; fn < 4; fn++) bval[fn] = bias[col0 + wn * 64 + fn * 16 + l15];
#pragma unroll
    for (int fm = 0; fm < 8; fm++) {
#pragma unroll
      for (int fn = 0; fn < 4; fn++) {
        const int col = col0 + wn * 64 + fn * 16 + l15;
        const int i = (col & (HD - 1)) >> 1;
#pragma unroll
        for (int r = 0; r < 4; r++) {
          const int row = row0 + wm * 128 + fm * 16 + 4 * g + r;
          float y = acc[fm][fn][r] + bval[fn];
          float p = __shfl_xor(y, 1);
          const int spos = sp + (row & (S_LEN - 1));
          const float c = fcos[spos * (HD / 2) + i];
          const float sn = fsin[spos * (HD / 2) + i];
          y = (col & 1) ? (p * sn + y * c) : (y * c - p * sn);
          C[(size_t)row * N + col] = (__bf16)(y * scale);
        }
      }
    }
  }
}

// ------- fused K+V projection GEMM; V written DIRECTLY transposed to Vt -------
__global__ __launch_bounds__(256) void gemm_kv(
    const __bf16* __restrict__ A,
    const __bf16* __restrict__ Wk, const float* __restrict__ bk, __bf16* __restrict__ Ko,
    const __bf16* __restrict__ Wv, const float* __restrict__ bv, __bf16* __restrict__ Vt,
    const float* __restrict__ fcos, const float* __restrict__ fsin,
    const int* __restrict__ sp_ptr)
{
  constexpr int N = 512, K = 3584;
  __shared__ __bf16 As[128 * 32];
  __shared__ __bf16 Bs[128 * 32];
  const int tid = threadIdx.x;
  const int lane = tid & 63, wid = tid >> 6;
  const int l15 = lane & 15, g = lane >> 4;
  const int wr = wid >> 1, wc = wid & 1;
  const bool isK = blockIdx.x < 4;
  const __bf16* Bw = isK ? Wk : Wv;
  const float* bias = isK ? bk : bv;
  const int row0 = blockIdx.y * 128;
  const int col0 = (blockIdx.x & 3) * 128;

  f32x4 acc[4][4] = {};

  const int srow = tid >> 2;
  const int scol = (tid & 3) * 8;
  const __bf16* Ag0 = A + (size_t)(row0 + srow) * K + scol;
  const __bf16* Ag1 = Ag0 + (size_t)64 * K;
  const __bf16* Bg0 = Bw + (size_t)(col0 + srow) * K + scol;
  const __bf16* Bg1 = Bg0 + (size_t)64 * K;
  __bf16* As0 = As + tid * 8;
  __bf16* As1 = As + 2048 + tid * 8;
  __bf16* Bs0 = Bs + tid * 8;
  __bf16* Bs1 = Bs + 2048 + tid * 8;

  for (int k0 = 0; k0 < K; k0 += 32) {
    GLDS16(Ag0 + k0, As0);
    GLDS16(Ag1 + k0, As1);
    GLDS16(Bg0 + k0, Bs0);
    GLDS16(Bg1 + k0, Bs1);
    __syncthreads();
    bf16x8 af[4], bfr[4];
#pragma unroll
    for (int m = 0; m < 4; m++)
      af[m] = *reinterpret_cast<const bf16x8*>(As + (wr * 64 + m * 16 + l15) * 32 + g * 8);
#pragma unroll
    for (int n = 0; n < 4; n++)
      bfr[n] = *reinterpret_cast<const bf16x8*>(Bs + (wc * 64 + n * 16 + l15) * 32 + g * 8);
#pragma unroll
    for (int m = 0; m < 4; m++)
#pragma unroll
      for (int n = 0; n < 4; n++)
        acc[m][n] = __builtin_amdgcn_mfma_f32_16x16x32_bf16(af[m], bfr[n], acc[m][n], 0, 0, 0);
    __syncthreads();
  }

  const int sp = sp_ptr[0];
  if (isK) {
#pragma unroll
    for (int m = 0; m < 4; m++) {
#pragma unroll
      for (int n = 0; n < 4; n++) {
        const int col = col0 + wc * 64 + n * 16 + l15;
        const float bval = bias[col];
        f32x4 v = acc[m][n];
#pragma unroll
        for (int r = 0; r < 4; r++) {
          const int row = row0 + wr * 64 + m * 16 + 4 * g + r;
          float y = v[r] + bval;
          float p = __shfl_xor(y, 1);
          const int i = (col & (HD - 1)) >> 1;
          const int spos = sp + (row & (S_LEN - 1));
          const float c = fcos[spos * (HD / 2) + i];
          const float sn = fsin[spos * (HD / 2) + i];
          y = (col & 1) ? (p * sn + y * c) : (y * c - p * sn);
          Ko[(size_t)row * N + col] = (__bf16)y;
        }
      }
    }
  } else {
    const int b4kv = ((row0 >> 11) * 4) + (blockIdx.x & 3);
    __bf16* vbase = Vt + ((size_t)b4kv << 18);  // 128*2048
#pragma unroll
    for (int m = 0; m < 4; m++) {
#pragma unroll
      for (int n = 0; n < 4; n++) {
        const int d = wc * 64 + n * 16 + l15;
        const float bval = bias[col0 + d];
        const int s0 = (row0 + wr * 64 + m * 16 + 4 * g) & (S_LEN - 1);
        f32x4 v = acc[m][n];
        bf16x4 o;
#pragma unroll
        for (int r = 0; r < 4; r++) o[r] = (__bf16)(v[r] + bval);
        *reinterpret_cast<bf16x4*>(vbase + (size_t)d * S_LEN + s0) = o;
      }
    }
  }
}

// -------- Flash attention: persistent blocks + LPT dynamic work queue,
// double-buffered K/V (best-measured R13 structure) --------
__global__ __launch_bounds__(256, 2) void attn_kernel(
    const __bf16* __restrict__ Qb, const __bf16* __restrict__ Kb,
    const __bf16* __restrict__ Vt, __bf16* __restrict__ Ob, int* __restrict__ ctr)
{
  __shared__ __align__(16) char asmem[65536];
  __shared__ int jsh;

  const int tid = threadIdx.x, lane = tid & 63, wid = tid >> 6;
  const int l31 = lane & 31, hh = lane >> 5;

  const int trow = tid >> 4;
  const int kcol = (((tid & 15) * 16) ^ ((trow & 7) << 4)) >> 1;
  const int vrow = tid >> 3;
  const int vcol = (((tid & 7) * 16) ^ ((vrow & 7) << 4)) >> 1;

  constexpr int NITEMS = 16 * NH * 2;  // 896

  while (true) {
    if (tid == 0) jsh = atomicAdd(ctr, 1);
    __syncthreads();
    const int j = jsh;
    if (j >= NITEMS) break;

    const int qi = 15 - (j / 56);
    const int r56 = j % 56;
    const int h = r56 >> 1, b = r56 & 1;
    const int kvh = h / NREP;
    const int qw = qi * 128 + wid * 32;
    const int qg = qw + l31;

    const __bf16* Kbase = Kb + ((size_t)b * S_LEN * NKV + kvh) * HD;
    const __bf16* Vbase = Vt + ((size_t)b * NKV + kvh) * (size_t)HD * S_LEN;

    bf16x8 qf[8];
    {
      const __bf16* qp = Qb + (((size_t)b * S_LEN + qg) * NH + h) * HD + hh * 8;
#pragma unroll
      for (int c = 0; c < 8; c++) qf[c] = *reinterpret_cast<const bf16x8*>(qp + c * 16);
    }

    f32x16 o[4] = {};
    float mrun = -3.0e38f, lsum = 0.0f;

    const int ntiles = 2 * qi + 2;  // always even -> last tile reads slot 1

#define STAGE(T, S)                                                                     \
    do {                                                                                \
      const int k0_ = (T) * 64;                                                         \
      char* Kd_ = asmem + (S) * 32768;                                                  \
      char* Vd_ = Kd_ + 16384;                                                          \
      _Pragma("unroll")                                                                 \
      for (int p = 0; p < 4; p++) {                                                     \
        GLDS16(Kbase + (size_t)(k0_ + p * 16 + trow) * (NKV * HD) + kcol,               \
               Kd_ + (p * 256 + tid) * 16);                                             \
        GLDS16(Vbase + (size_t)(p * 32 + vrow) * S_LEN + k0_ + vcol,                    \
               Vd_ + (p * 256 + tid) * 16);                                             \
      }                                                                                 \
    } while (0)

    STAGE(0, 0);

    for (int t = 0; t < ntiles; t++) {
      __syncthreads();  // drains tile t's staging loads + joins waves
      if (t + 1 < ntiles) STAGE(t + 1, (t + 1) & 1);

      const char* Ksb = asmem + (t & 1) * 32768;
      const char* Vsb = Ksb + 16384;
      const int k0 = t * 64;

      f32x16 s0 = {}, s1 = {};
      {
        const char* kp0 = Ksb + l31 * 256;
        const char* kp1 = kp0 + 32 * 256;
        const int sw = (l31 & 7) << 4;
        __builtin_amdgcn_s_setprio(1);
#pragma unroll
        for (int c = 0; c < 8; c++) {
          const int cb = (c * 32 + hh * 16) ^ sw;
          bf16x8 kf0 = *reinterpret_cast<const bf16x8*>(kp0 + cb);
          s0 = __builtin_amdgcn_mfma_f32_32x32x16_bf16(kf0, qf[c], s0, 0, 0, 0);
          bf16x8 kf1 = *reinterpret_cast<const bf16x8*>(kp1 + cb);
          s1 = __builtin_amdgcn_mfma_f32_32x32x16_bf16(kf1, qf[c], s1, 0, 0, 0);
        }
        __builtin_amdgcn_s_setprio(0);
      }

      if (k0 + 63 > qw) {
#pragma unroll
        for (int r = 0; r < 16; r++) {
          const int kvo = k0 + ((r & 3) + 8 * (r >> 2)) + 4 * hh;
          if (kvo > qg)      s0[r] = -1.0e9f;
          if (kvo + 32 > qg) s1[r] = -1.0e9f;
        }
      }

      float pmax = -3.0e38f;
#pragma unroll
      for (int r = 0; r < 16; r++) { pmax = fmaxf(pmax, s0[r]); pmax = fmaxf(pmax, s1[r]); }
      pmax = fmaxf(pmax, __shfl_xor(pmax, 32));
      if (!__all(pmax <= mrun + 11.5f)) {
        const float mnew = fmaxf(mrun, pmax);
        const float fs = exp2f(mrun - mnew);
        lsum *= fs;
#pragma unroll
        for (int dt = 0; dt < 4; dt++) o[dt] *= fs;
        mrun = mnew;
      }
      float psum = 0.0f;
#pragma unroll
      for (int r = 0; r < 16; r++) {
        s0[r] = exp2f(s0[r] - mrun); psum += s0[r];
        s1[r] = exp2f(s1[r] - mrun); psum += s1[r];
      }
      lsum += psum;

      unsigned int pk[2][8], px[2][8];
#pragma unroll
      for (int jj = 0; jj < 8; jj++) {
        pk[0][jj] = pack2(s0[2 * jj], s0[2 * jj + 1]);
        pk[1][jj] = pack2(s1[2 * jj], s1[2 * jj + 1]);
      }
#pragma unroll
      for (int tt = 0; tt < 2; tt++)
#pragma unroll
        for (int jj = 0; jj < 8; jj++) px[tt][jj] = __shfl_xor(pk[tt][jj], 32);

      __builtin_amdgcn_s_setprio(1);
#pragma unroll
      for (int tt = 0; tt < 2; tt++) {
#pragma unroll
        for (int c2 = 0; c2 < 2; c2++) {
          u32x4 pb4;
          if (hh == 0)
            pb4 = (u32x4){pk[tt][4 * c2], pk[tt][4 * c2 + 1], px[tt][4 * c2], px[tt][4 * c2 + 1]};
          else
            pb4 = (u32x4){px[tt][4 * c2 + 2], px[tt][4 * c2 + 3], pk[tt][4 * c2 + 2], pk[tt][4 * c2 + 3]};
          bf16x8 pbf = __builtin_bit_cast(bf16x8, pb4);
          const int colb = tt * 64 + c2 * 32 + hh * 16;
#pragma unroll
          for (int dt = 0; dt < 4; dt++) {
            const int d = dt * 32 + l31;
            bf16x8 vf = *reinterpret_cast<const bf16x8*>(Vsb + d * 128 + (colb ^ ((d & 7) << 4)));
            o[dt] = __builtin_amdgcn_mfma_f32_32x32x16_bf16(vf, pbf, o[dt], 0, 0, 0);
          }
        }
      }
      __builtin_amdgcn_s_setprio(0);
    }
#undef STAGE

    lsum += __shfl_xor(lsum, 32);
    const float inv = 1.0f / lsum;
    char* my = asmem + wid * 8192;
#pragma unroll
    for (int dt = 0; dt < 4; dt++) {
#pragma unroll
      for (int jj = 0; jj < 8; jj++) {
        const int r = 2 * jj;
        const int d = dt * 32 + ((r & 3) + 8 * (r >> 2)) + 4 * hh;
        const unsigned int w = pack2(o[dt][r] * inv, o[dt][r + 1] * inv);
        *reinterpret_cast<unsigned int*>(my + ((l31 * 256 + d * 2) ^ ((l31 & 7) << 4))) = w;
      }
    }
#pragma unroll
    for (int jj = 0; jj < 8; jj++) {
      const int idx = jj * 64 + lane;
      const int row = idx >> 4, c16 = idx & 15;
      u32x4 val = *reinterpret_cast<u32x4*>(my + row * 256 + ((c16 * 16) ^ ((row & 7) << 4)));
      *reinterpret_cast<u32x4*>(Ob + (size_t)(b * S_LEN + qw + row) * (NH * HD) + h * HD + c16 * 8) = val;
    }
  }
}

// ---------------- launch ----------------
extern "C" void kernel_launch(void* const* d_in, const int* in_sizes, int n_in,
                              void* d_out, int out_size, void* d_ws, size_t ws_size,
                              hipStream_t stream) {
  (void)in_sizes; (void)n_in; (void)out_size; (void)ws_size;
  const float* x    = (const float*)d_in[0];
  const float* wq_w = (const float*)d_in[1];
  const float* wq_b = (const float*)d_in[2];
  const float* wk_w = (const float*)d_in[3];
  const float* wk_b = (const float*)d_in[4];
  const float* wv_w = (const float*)d_in[5];
  const float* wv_b = (const float*)d_in[6];
  const float* wo_w = (const float*)d_in[7];
  const float* fcos = (const float*)d_in[10];
  const float* fsin = (const float*)d_in[11];
  const int*   spp  = (const int*)d_in[13];
  float* out = (float*)d_out;

  constexpr size_t XB_N = (size_t)4096 * 3584;
  constexpr size_t WQ_N = (size_t)3584 * 3584;
  constexpr size_t WK_N = (size_t)512 * 3584;
  constexpr size_t WO_N = (size_t)3584 * 3584;
  constexpr size_t KB_N = (size_t)4096 * 512;

  __bf16* xb  = (__bf16*)d_ws;
  __bf16* wqb = xb + XB_N;
  __bf16* wkb = wqb + WQ_N;
  __bf16* wvb = wkb + WK_N;
  __bf16* wob = wvb + WK_N;
  __bf16* Qb  = wob + WO_N;
  __bf16* Kb  = Qb + XB_N;
  __bf16* Vt  = Kb + KB_N;
  int*    ctr = (int*)(Vt + KB_N);
  __bf16* Ob  = xb;  // alias: xb dead after QKV GEMMs (stream-ordered)

  constexpr int N0 = (int)(XB_N / 4), N1 = (int)(WQ_N / 4), N2 = (int)(WK_N / 4),
                N3 = (int)(WK_N / 4), N4 = (int)(WO_N / 4);
  constexpr int NTOT = N0 + N1 + N2 + N3 + N4;
  cvt5_kernel<<<2048, 256, 0, stream>>>(x, wq_w, wk_w, wv_w, wo_w,
                                        xb, wqb, wkb, wvb, wob,
                                        N0, N1, N2, N3, ctr, NTOT);

  gemm256<2><<<dim3(224), 512, 131072, stream>>>(xb, wqb, wq_b, Qb, 4096, 3584, 3584,
                                                 fcos, fsin, spp, SCALE_LOG2);
  gemm_kv<<<dim3(8, 32), 256, 0, stream>>>(xb, wkb, wk_b, Kb, wvb, wv_b, Vt,
                                           fcos, fsin, spp);
  attn_kernel<<<dim3(512), 256, 0, stream>>>(Qb, Kb, Vt, Ob, ctr);
  gemm256<0><<<dim3(224), 512, 131072, stream>>>(Ob, wob, nullptr, out, 4096, 3584, 3584,
                                                 nullptr, nullptr, nullptr, 1.0f);
}